// Round 1
// baseline (96.003 us; speedup 1.0000x reference)
//
#include <hip/hip_runtime.h>

// Problem constants (fixed by the reference):
//   B=4096, L=200, EMBEDDING_DIM=100, C=2 chunks of M=50, VOCAB=100000
constexpr int C_ = 2;
constexpr int M_ = 50;
constexpr int ED = 100;
constexpr float EPS = 1e-8f;

// tbl layout per row: (a0, a0*dw0, a1, a1*dw1)

// ---------------------------------------------------------------------------
// Pass 1: per-vocab-row statistics. ONE THREAD PER ROW.
//   Each thread streams its 400-byte row as 25 aligned float4 loads
//   (row base = 400*r, 400 % 16 == 0 so every row is 16B-aligned) and
//   accumulates, per chunk c in {0,1}:
//     sq_c = ||x_c||^2,  du_c = x_c . u_c,  dw_c = x_c . w_c
//   entirely in registers (6 scalar accumulators, no per-thread array).
//   Chunk membership of element e=4j+k is compile-time constant under the
//   full unroll, so there is zero branching. A wave reads 64 rows = 25.6 KB
//   of CONTIGUOUS memory (dense, fully-used lines), and writes one
//   coalesced float4 per row. vs the previous 2-waves-per-64-rows version:
//   half the threads, half the instruction overhead, one store not two.
// ---------------------------------------------------------------------------
__global__ __launch_bounds__(256) void row_stats_kernel(
    const float* __restrict__ emb,   // [VOCAB, 100]
    const float* __restrict__ wgt,   // [100]
    const float* __restrict__ att,   // [100] = [2,50]
    float*       __restrict__ tbl,   // [VOCAB * 4]
    int vocab)
{
    __shared__ float2 s_uw[ED];   // (attend_u[e], weights[e])
    __shared__ float  s_su[C_];   // 1 / max(||u_c||, eps)

    const int t = threadIdx.x;
    if (t < ED) s_uw[t] = make_float2(att[t], wgt[t]);
    __syncthreads();
    if (t < C_) {
        float ss = 0.f;
        #pragma unroll
        for (int m = 0; m < M_; ++m) { float v = s_uw[t * M_ + m].x; ss += v * v; }
        s_su[t] = 1.0f / fmaxf(sqrtf(ss), EPS);
    }
    __syncthreads();

    const int r = blockIdx.x * 256 + t;       // row
    if (r >= vocab) return;

    const float4* rowp = reinterpret_cast<const float4*>(emb + (long long)r * ED);

    float sq0 = 0.f, du0 = 0.f, dw0 = 0.f;
    float sq1 = 0.f, du1 = 0.f, dw1 = 0.f;

    #pragma unroll
    for (int j = 0; j < 25; ++j) {
        const float4 v = rowp[j];
        const float vals[4] = { v.x, v.y, v.z, v.w };
        #pragma unroll
        for (int k = 0; k < 4; ++k) {
            const int e = 4 * j + k;          // compile-time constant
            const float2 uw = s_uw[e];        // wave-uniform broadcast: free
            const float x = vals[k];
            if (e < M_) {                     // chunk 0 (compile-time branch)
                sq0 = fmaf(x, x, sq0);
                du0 = fmaf(x, uw.x, du0);
                dw0 = fmaf(x, uw.y, dw0);
            } else {                          // chunk 1
                sq1 = fmaf(x, x, sq1);
                du1 = fmaf(x, uw.x, du1);
                dw1 = fmaf(x, uw.y, dw1);
            }
        }
    }

    // identical math to the verified version (div by max(sqrt, eps), not rsqrt)
    const float cos0 = du0 / fmaxf(sqrtf(sq0), EPS) * s_su[0];
    const float cos1 = du1 / fmaxf(sqrtf(sq1), EPS) * s_su[1];
    const float a0 = __expf(cos0);
    const float a1 = __expf(cos1);

    reinterpret_cast<float4*>(tbl)[r] = make_float4(a0, a0 * dw0, a1, a1 * dw1);
}

// ---------------------------------------------------------------------------
// Pass 2: one WAVE per batch element. out[b] = P0/A0 + P1/A1 over L gathered
// table entries (16 B each, 1.6 MB table is L2/L3-resident). No __syncthreads.
// (unchanged from the harness-verified version)
// ---------------------------------------------------------------------------
__global__ __launch_bounds__(256) void attend_kernel(
    const int*    __restrict__ idx,  // [B, L]
    const float4* __restrict__ tbl,  // [VOCAB] as (a0, ap0, a1, ap1)
    float*        __restrict__ out,  // [B]
    int B, int L)
{
    const int wave = threadIdx.x >> 6;
    const int lane = threadIdx.x & 63;
    const int b    = blockIdx.x * 4 + wave;
    if (b >= B) return;

    const int* ib = idx + (long long)b * L;
    float a0 = 0.f, a1 = 0.f, ap0 = 0.f, ap1 = 0.f;
    #pragma unroll 4
    for (int l = lane; l < L; l += 64) {       // coalesced idx read, cached gather
        const float4 v = tbl[ib[l]];
        a0 += v.x; ap0 += v.y; a1 += v.z; ap1 += v.w;
    }

    #pragma unroll
    for (int off = 32; off > 0; off >>= 1) {
        a0  += __shfl_down(a0,  off, 64);
        a1  += __shfl_down(a1,  off, 64);
        ap0 += __shfl_down(ap0, off, 64);
        ap1 += __shfl_down(ap1, off, 64);
    }
    if (lane == 0) out[b] = ap0 / a0 + ap1 / a1;
}

extern "C" void kernel_launch(void* const* d_in, const int* in_sizes, int n_in,
                              void* d_out, int out_size, void* d_ws, size_t ws_size,
                              hipStream_t stream) {
    const int*   idx = (const int*)d_in[0];    // word_idxs [4096,200] int32
    const float* emb = (const float*)d_in[1];  // emb_table [100000,100] f32
    const float* wgt = (const float*)d_in[2];  // weights   [100,1] f32
    const float* att = (const float*)d_in[3];  // attend_u  [2,50] f32
    float* out = (float*)d_out;                // [4096] f32

    const int B     = out_size;                 // 4096
    const int L     = in_sizes[0] / B;          // 200
    const int vocab = in_sizes[1] / ED;         // 100000

    float* tbl = (float*)d_ws;                  // 100000 * 16 B = 1.6 MB scratch

    row_stats_kernel<<<(vocab + 255) / 256, 256, 0, stream>>>(emb, wgt, att, tbl, vocab);
    attend_kernel<<<(B + 3) / 4, 256, 0, stream>>>(idx, (const float4*)tbl, out, B, L);
}

// Round 2
// 92.541 us; speedup vs baseline: 1.0374x; 1.0374x over previous
//
#include <hip/hip_runtime.h>

// Problem constants (fixed by the reference):
//   B=4096, L=200, EMBEDDING_DIM=100, C=2 chunks of M=50, VOCAB=100000
constexpr int C_ = 2;
constexpr int M_ = 50;
constexpr int ED = 100;
constexpr float EPS = 1e-8f;

// tbl layout per row: (a0, a0*dw0, a1, a1*dw1)

// ---------------------------------------------------------------------------
// Pass 1: per-vocab-row statistics. FOUR LANES PER ROW.
//   Lane group {4g..4g+3} of a wave owns row r; lane j reads float4s
//   j, 4+j, 8+j, ..., 20+j  (f = 4*it + j, it=0..5), so the 4 lanes of a
//   group read 4 CONSECUTIVE float4 = exactly one 64B cache line, and each
//   wave-load instruction touches 16 fully-utilized lines (the optimum for
//   64 lanes x 16B). No reliance on L1 line survival, 4x the wave-level
//   parallelism of one-thread-per-row (400K threads) to hide HBM latency.
//   float4 #24 (elements 96..99) is a j==0 tail; float4 #12 straddles the
//   chunk boundary (e=48..51) and is the only runtime-chunk case.
//   Partial (sq,du,dw) per chunk are tree-reduced across the 4 lanes with
//   quad shuffles; lane j==0 finishes (cos, exp) and stores one float4.
// ---------------------------------------------------------------------------
__global__ __launch_bounds__(256) void row_stats_kernel(
    const float* __restrict__ emb,   // [VOCAB, 100]
    const float* __restrict__ wgt,   // [100]
    const float* __restrict__ att,   // [100] = [2,50]
    float*       __restrict__ tbl,   // [VOCAB * 4]
    int vocab)
{
    __shared__ float2 s_uw[ED];   // (attend_u[e], weights[e])
    __shared__ float  s_su[C_];   // 1 / max(||u_c||, eps)

    const int t = threadIdx.x;
    if (t < ED) s_uw[t] = make_float2(att[t], wgt[t]);
    __syncthreads();
    if (t < C_) {
        float ss = 0.f;
        #pragma unroll
        for (int m = 0; m < M_; ++m) { float v = s_uw[t * M_ + m].x; ss += v * v; }
        s_su[t] = 1.0f / fmaxf(sqrtf(ss), EPS);
    }
    __syncthreads();

    const int wave = t >> 6;
    const int lane = t & 63;
    const int g    = lane >> 2;               // row-in-wave (0..15)
    const int j    = lane & 3;                // float4 slot within group
    const int r    = blockIdx.x * 64 + wave * 16 + g;
    if (r >= vocab) return;

    const float4* rowp = reinterpret_cast<const float4*>(emb + (long long)r * ED);

    float sq0 = 0.f, du0 = 0.f, dw0 = 0.f;
    float sq1 = 0.f, du1 = 0.f, dw1 = 0.f;

    #pragma unroll
    for (int it = 0; it < 6; ++it) {
        const float4 v = rowp[4 * it + j];    // 4 lanes -> one full 64B line
        const float xs[4] = { v.x, v.y, v.z, v.w };
        #pragma unroll
        for (int k = 0; k < 4; ++k) {
            const int ebase = 16 * it + k;    // element e = ebase + 4*j
            const float x   = xs[k];
            const float2 uw = s_uw[ebase + 4 * j];
            if (ebase + 12 < M_) {            // e<50 for every j: chunk 0
                sq0 = fmaf(x, x, sq0); du0 = fmaf(x, uw.x, du0); dw0 = fmaf(x, uw.y, dw0);
            } else if (ebase >= M_) {         // e>=50 for every j: chunk 1
                sq1 = fmaf(x, x, sq1); du1 = fmaf(x, uw.x, du1); dw1 = fmaf(x, uw.y, dw1);
            } else {                          // it==3, k<2: j==0 is chunk0, else chunk1
                if (j == 0) { sq0 = fmaf(x, x, sq0); du0 = fmaf(x, uw.x, du0); dw0 = fmaf(x, uw.y, dw0); }
                else        { sq1 = fmaf(x, x, sq1); du1 = fmaf(x, uw.x, du1); dw1 = fmaf(x, uw.y, dw1); }
            }
        }
    }
    if (j == 0) {                             // tail float4 #24: elements 96..99
        const float4 v = rowp[24];
        const float xs[4] = { v.x, v.y, v.z, v.w };
        #pragma unroll
        for (int k = 0; k < 4; ++k) {
            const float2 uw = s_uw[96 + k];
            sq1 = fmaf(xs[k], xs[k], sq1); du1 = fmaf(xs[k], uw.x, du1); dw1 = fmaf(xs[k], uw.y, dw1);
        }
    }

    // reduce the 6 partials across the 4 lanes of the group (quad shuffles)
    #pragma unroll
    for (int m = 1; m < 4; m <<= 1) {
        sq0 += __shfl_xor(sq0, m, 4);
        du0 += __shfl_xor(du0, m, 4);
        dw0 += __shfl_xor(dw0, m, 4);
        sq1 += __shfl_xor(sq1, m, 4);
        du1 += __shfl_xor(du1, m, 4);
        dw1 += __shfl_xor(dw1, m, 4);
    }

    if (j == 0) {
        const float cos0 = du0 / fmaxf(sqrtf(sq0), EPS) * s_su[0];
        const float cos1 = du1 / fmaxf(sqrtf(sq1), EPS) * s_su[1];
        const float a0 = __expf(cos0);
        const float a1 = __expf(cos1);
        reinterpret_cast<float4*>(tbl)[r] = make_float4(a0, a0 * dw0, a1, a1 * dw1);
    }
}

// ---------------------------------------------------------------------------
// Pass 2: TWO waves per batch element (block = 256 threads = 2 batch elems).
//   Grid 2048 blocks -> 8 blocks/CU = 32 waves/CU (max occupancy) to hide
//   the random-gather latency on the 1.6 MB table. Each thread gathers at
//   most 2 entries (l = tt, tt+128); wave-level shuffle reduce, then the two
//   wave partials per batch element combine through a 4-entry LDS stage.
// ---------------------------------------------------------------------------
__global__ __launch_bounds__(256) void attend_kernel(
    const int*    __restrict__ idx,  // [B, L]
    const float4* __restrict__ tbl,  // [VOCAB] as (a0, ap0, a1, ap1)
    float*        __restrict__ out,  // [B]
    int B, int L)
{
    __shared__ float4 s_part[4];

    const int half = threadIdx.x >> 7;        // which batch element in block
    const int tt   = threadIdx.x & 127;       // thread within the pair of waves
    const int b    = blockIdx.x * 2 + half;

    float a0 = 0.f, ap0 = 0.f, a1 = 0.f, ap1 = 0.f;
    if (b < B) {
        const int* ib = idx + (long long)b * L;
        #pragma unroll 2
        for (int l = tt; l < L; l += 128) {   // coalesced idx read, cached gather
            const float4 v = tbl[ib[l]];
            a0 += v.x; ap0 += v.y; a1 += v.z; ap1 += v.w;
        }
        #pragma unroll
        for (int off = 32; off > 0; off >>= 1) {
            a0  += __shfl_down(a0,  off, 64);
            a1  += __shfl_down(a1,  off, 64);
            ap0 += __shfl_down(ap0, off, 64);
            ap1 += __shfl_down(ap1, off, 64);
        }
    }

    const int wave = threadIdx.x >> 6;
    if ((threadIdx.x & 63) == 0) s_part[wave] = make_float4(a0, ap0, a1, ap1);
    __syncthreads();

    if (tt == 0 && b < B) {
        const float4 p = s_part[half * 2];
        const float4 q = s_part[half * 2 + 1];
        out[b] = (p.y + q.y) / (p.x + q.x) + (p.w + q.w) / (p.z + q.z);
    }
}

extern "C" void kernel_launch(void* const* d_in, const int* in_sizes, int n_in,
                              void* d_out, int out_size, void* d_ws, size_t ws_size,
                              hipStream_t stream) {
    const int*   idx = (const int*)d_in[0];    // word_idxs [4096,200] int32
    const float* emb = (const float*)d_in[1];  // emb_table [100000,100] f32
    const float* wgt = (const float*)d_in[2];  // weights   [100,1] f32
    const float* att = (const float*)d_in[3];  // attend_u  [2,50] f32
    float* out = (float*)d_out;                // [4096] f32

    const int B     = out_size;                 // 4096
    const int L     = in_sizes[0] / B;          // 200
    const int vocab = in_sizes[1] / ED;         // 100000

    float* tbl = (float*)d_ws;                  // 100000 * 16 B = 1.6 MB scratch

    row_stats_kernel<<<(vocab + 63) / 64, 256, 0, stream>>>(emb, wgt, att, tbl, vocab);
    attend_kernel<<<(B + 1) / 2, 256, 0, stream>>>(idx, (const float4*)tbl, out, B, L);
}